// Round 1
// baseline (710.324 us; speedup 1.0000x reference)
//
#include <hip/hip_runtime.h>
#include <hip/hip_bf16.h>

#define EDGES 600000
#define DIN 128
#define DHID 256
#define DOUT 128
#define BLK_EDGES 128
#define SSTRIDE 136  // shorts per s row: 128 + 8 pad -> conflict-friendly

typedef __attribute__((ext_vector_type(4))) float floatx4;
typedef __attribute__((ext_vector_type(4))) short shortx4;
typedef __attribute__((ext_vector_type(8))) short shortx8;

__device__ inline unsigned short f2bf_rne(float f) {
    union { float f; unsigned u; } v; v.f = f;
    unsigned r = v.u + 0x7FFFu + ((v.u >> 16) & 1u);
    return (unsigned short)(r >> 16);
}

// Pre-pass: convert W1/W2 fp32 -> bf16, swizzled fragment-major so the main
// kernel's weight loads are fully coalesced per-wave streams.
// W1s: frag (t,ks): 64 lanes x 8 bf16  (A-frag of 16x16x32: m=lane&15, k=q*8+j)
// W2s: frag (t,ot): 64 lanes x 4 bf16  (B-frag of 16x16x16: n=lane&15, k=q*4+j)
__global__ __launch_bounds__(256) void prep_kernel(
        const float* __restrict__ W1, const float* __restrict__ W2,
        unsigned short* __restrict__ ws) {
    int j = blockIdx.x * 256 + threadIdx.x;
    if (j < 4096) {                       // W1 frags: 16 t * 4 ks * 64 lanes
        int lane = j & 63, fs = j >> 6;
        int ks = fs & 3, t = fs >> 2;
        int hid = t * 16 + (lane & 15), q = lane >> 4;
        const float* src = W1 + hid * DIN + ks * 32 + q * 8;
        shortx8 v;
        #pragma unroll
        for (int i = 0; i < 8; ++i) v[i] = (short)f2bf_rne(src[i]);
        *((shortx8*)ws + j) = v;
    } else if (j < 12288) {               // W2 frags: 16 t * 8 ot * 64 lanes
        int j2 = j - 4096;
        int lane = j2 & 63, fs = j2 >> 6;
        int ot = fs & 7, t = fs >> 3;     // layout (t*8+ot)*64+lane
        int o = ot * 16 + (lane & 15), q = lane >> 4;
        const float* src = W2 + o * DHID + t * 16 + q * 4;
        shortx4 v;
        #pragma unroll
        for (int i = 0; i < 4; ++i) v[i] = (short)f2bf_rne(src[i]);
        *((shortx4*)(ws + 32768) + j2) = v;
    }
}

// Fused: gather s = x[src]+x[dst] -> bf16 LDS; per wave (32 edges):
// GEMM1 transposed (hT = W1 s^T, 16x16x32) so the C-layout of acc1
// (col=edge, row=hid=4q+r) IS the A-layout of 16x16x16 GEMM2 (m=edge,
// k=4q+j) -> relu+bias+cvt in regs feeds GEMM2 with no LDS round-trip.
__global__ __launch_bounds__(256, 2) void gin_kernel(
        const float* __restrict__ x, const int* __restrict__ ei,
        const float* __restrict__ b1, const float* __restrict__ b2,
        const unsigned short* __restrict__ wsw,
        float* __restrict__ out) {
    __shared__ short s_lds[BLK_EDGES * SSTRIDE];
    const int tid = threadIdx.x;
    const int ebase = blockIdx.x * BLK_EDGES;

    // ---- stage 1: gather + convert into LDS ----
    {
        const int e = tid >> 1, p = tid & 1;
        const int eg = ebase + e;
        if (eg < EDGES) {
            const int na = ei[eg];
            const int nb = ei[EDGES + eg];
            const float4* xa = (const float4*)(x + (size_t)na * DIN);
            const float4* xb = (const float4*)(x + (size_t)nb * DIN);
            short* dst = s_lds + e * SSTRIDE;
            #pragma unroll
            for (int i = 0; i < 8; ++i) {
                const int c = 2 * i + p;      // 8-float chunk index 0..15
                float4 u0 = xa[2 * c], u1 = xa[2 * c + 1];
                float4 v0 = xb[2 * c], v1 = xb[2 * c + 1];
                union { shortx8 s8; __hip_bfloat162 b[4]; } pk;
                pk.b[0] = __float22bfloat162_rn(make_float2(u0.x + v0.x, u0.y + v0.y));
                pk.b[1] = __float22bfloat162_rn(make_float2(u0.z + v0.z, u0.w + v0.w));
                pk.b[2] = __float22bfloat162_rn(make_float2(u1.x + v1.x, u1.y + v1.y));
                pk.b[3] = __float22bfloat162_rn(make_float2(u1.z + v1.z, u1.w + v1.w));
                *(shortx8*)(dst + c * 8) = pk.s8;
            }
        }
    }
    __syncthreads();

    // ---- stage 2 ----
    const int wave = tid >> 6, lane = tid & 63;
    const int q = lane >> 4, col = lane & 15;
    const int wbase = wave * 32;   // wave's 32 edges within block

    // preload this wave's entire s slice as B-frags (B[n=edge][k=din])
    shortx8 sfrag[2][4];
    #pragma unroll
    for (int g = 0; g < 2; ++g)
        #pragma unroll
        for (int ks = 0; ks < 4; ++ks)
            sfrag[g][ks] = *(const shortx8*)(s_lds + (wbase + g * 16 + col) * SSTRIDE
                                             + ks * 32 + q * 8);

    floatx4 acc2[2][8];
    #pragma unroll
    for (int g = 0; g < 2; ++g)
        #pragma unroll
        for (int ot = 0; ot < 8; ++ot)
            acc2[g][ot] = (floatx4)0.0f;

    const shortx8* w1f = (const shortx8*)wsw + lane;
    const shortx4* w2f = (const shortx4*)(wsw + 32768) + lane;
    const float4* b1v4 = (const float4*)b1;

    #pragma unroll 1
    for (int t = 0; t < 16; ++t) {
        shortx8 a1[4];
        #pragma unroll
        for (int ks = 0; ks < 4; ++ks) a1[ks] = w1f[(t * 4 + ks) * 64];
        floatx4 acc1[2];
        acc1[0] = (floatx4)0.0f; acc1[1] = (floatx4)0.0f;
        #pragma unroll
        for (int ks = 0; ks < 4; ++ks) {
            acc1[0] = __builtin_amdgcn_mfma_f32_16x16x32_bf16(a1[ks], sfrag[0][ks], acc1[0], 0, 0, 0);
            acc1[1] = __builtin_amdgcn_mfma_f32_16x16x32_bf16(a1[ks], sfrag[1][ks], acc1[1], 0, 0, 0);
        }
        const float4 bv = b1v4[t * 4 + q];   // b1[t*16 + 4q + r], r=0..3
        shortx4 hf[2];
        #pragma unroll
        for (int g = 0; g < 2; ++g) {
            union { shortx4 s4; __hip_bfloat162 b[2]; } pk;
            pk.b[0] = __float22bfloat162_rn(make_float2(
                fmaxf(acc1[g][0] + bv.x, 0.0f), fmaxf(acc1[g][1] + bv.y, 0.0f)));
            pk.b[1] = __float22bfloat162_rn(make_float2(
                fmaxf(acc1[g][2] + bv.z, 0.0f), fmaxf(acc1[g][3] + bv.w, 0.0f)));
            hf[g] = pk.s4;
        }
        #pragma unroll
        for (int ot = 0; ot < 8; ++ot) {
            shortx4 wb = w2f[(t * 8 + ot) * 64];
            acc2[0][ot] = __builtin_amdgcn_mfma_f32_16x16x16bf16_1k(hf[0], wb, acc2[0][ot], 0, 0, 0);
            acc2[1][ot] = __builtin_amdgcn_mfma_f32_16x16x16bf16_1k(hf[1], wb, acc2[1][ot], 0, 0, 0);
        }
    }

    // ---- epilogue: out = 0.5*acc2 + 0.5*b2 ; D2 row=edge=4q+r, col=o ----
    const bool full = (ebase + BLK_EDGES <= EDGES);
    #pragma unroll
    for (int ot = 0; ot < 8; ++ot) {
        const float ob = 0.5f * b2[ot * 16 + col];
        #pragma unroll
        for (int g = 0; g < 2; ++g) {
            const int erow = ebase + wbase + g * 16 + q * 4;
            float* op = out + (size_t)erow * DOUT + ot * 16 + col;
            if (full) {
                #pragma unroll
                for (int r = 0; r < 4; ++r)
                    op[r * DOUT] = 0.5f * acc2[g][ot][r] + ob;
            } else {
                #pragma unroll
                for (int r = 0; r < 4; ++r)
                    if (erow + r < EDGES)
                        op[r * DOUT] = 0.5f * acc2[g][ot][r] + ob;
            }
        }
    }
}

extern "C" void kernel_launch(void* const* d_in, const int* in_sizes, int n_in,
                              void* d_out, int out_size, void* d_ws, size_t ws_size,
                              hipStream_t stream) {
    const float* x  = (const float*)d_in[0];
    const int*   ei = (const int*)d_in[1];     // edge_index as int32 per harness
    const float* W1 = (const float*)d_in[2];
    const float* b1 = (const float*)d_in[3];
    const float* W2 = (const float*)d_in[4];
    const float* b2 = (const float*)d_in[5];
    unsigned short* ws = (unsigned short*)d_ws;   // 64KB W1s + 64KB W2s

    prep_kernel<<<48, 256, 0, stream>>>(W1, W2, ws);
    const int nblk = (EDGES + BLK_EDGES - 1) / BLK_EDGES;   // 4688
    gin_kernel<<<nblk, 256, 0, stream>>>(x, ei, b1, b2, ws, (float*)d_out);
}